// Round 1
// baseline (554.069 us; speedup 1.0000x reference)
//
#include <hip/hip_runtime.h>

#define NLEVELS 16
#define LOG2T 19
#define TMASK ((1u << LOG2T) - 1u)
#define PRIME1 2654435761u

// One thread per (point b, level l), tid = b*16 + l.
//  - level-innermost => out writes are fully coalesced (each thread writes
//    one float2 at out[tid]); wave covers 4 points x 16 levels = 512B.
//  - res is a power of two for every level => x*res, floor, frac, and the
//    corner integer coords are bit-exact vs the f32 JAX reference.
__global__ __launch_bounds__(256) void hashgrid2d_kernel(
    const float* __restrict__ x,
    const float* __restrict__ tables,
    float* __restrict__ out,
    int B)
{
    int tid = blockIdx.x * blockDim.x + threadIdx.x;
    int b = tid >> 4;
    if (b >= B) return;
    int l = tid & 15;

    float2 xy = reinterpret_cast<const float2*>(x)[b];

    float res = (float)(256 << l);          // exact power of two
    float xs0 = xy.x * res;                 // exact (pow2 scale)
    float xs1 = xy.y * res;
    float v0 = floorf(xs0), v1 = floorf(xs1);
    float w0 = xs0 - v0,    w1 = xs1 - v1;

    unsigned i0 = (unsigned)(int)v0;
    unsigned i1 = (unsigned)(int)v1;

    unsigned hy0 = i1 * PRIME1;
    unsigned hy1 = hy0 + PRIME1;            // (i1+1)*PRIME1
    unsigned idx00 = ( i0        ^ hy0) & TMASK;
    unsigned idx01 = ( i0        ^ hy1) & TMASK;
    unsigned idx10 = ((i0 + 1u)  ^ hy0) & TMASK;
    unsigned idx11 = ((i0 + 1u)  ^ hy1) & TMASK;

    const float2* tbl = reinterpret_cast<const float2*>(tables)
                      + ((size_t)l << LOG2T);
    float2 e00 = tbl[idx00];
    float2 e01 = tbl[idx01];
    float2 e10 = tbl[idx10];
    float2 e11 = tbl[idx11];

    float omw0 = 1.0f - w0, omw1 = 1.0f - w1;
    // corner (0,0)/(1,0) lerp along dim0, then along dim1 — matches reference
    float c0x = e00.x * omw0 + e10.x * w0;
    float c0y = e00.y * omw0 + e10.y * w0;
    float c1x = e01.x * omw0 + e11.x * w0;
    float c1y = e01.y * omw0 + e11.y * w0;

    float2 o;
    o.x = c0x * omw1 + c1x * w1;
    o.y = c0y * omw1 + c1y * w1;
    reinterpret_cast<float2*>(out)[tid] = o;   // tid = b*16+l -> out[b][2l..2l+1]
}

extern "C" void kernel_launch(void* const* d_in, const int* in_sizes, int n_in,
                              void* d_out, int out_size, void* d_ws, size_t ws_size,
                              hipStream_t stream) {
    const float* x      = (const float*)d_in[0];
    const float* tables = (const float*)d_in[1];
    float* out          = (float*)d_out;
    int B = in_sizes[0] / 2;                 // x is (B, 2)

    int total  = B * NLEVELS;
    int block  = 256;
    int grid   = (total + block - 1) / block;
    hashgrid2d_kernel<<<grid, block, 0, stream>>>(x, tables, out, B);
}

// Round 2
// 551.908 us; speedup vs baseline: 1.0039x; 1.0039x over previous
//
#include <hip/hip_runtime.h>

#define NLEVELS 16
#define LOG2T 19
#define TMASK ((1u << LOG2T) - 1u)
#define PRIME1 2654435761u
#define THREADS 256
#define PTS_PER_THREAD 4
#define PTS_PER_BLOCK (THREADS * PTS_PER_THREAD)

typedef float vf2 __attribute__((ext_vector_type(2)));

// Level-partitioned hash-grid encode.
//  - Each block: ONE level x 1024 points. Table for one level = 4 MB = exactly
//    one XCD's L2. blockIdx swizzle: xcd = bid % 8 owns levels {2*xcd, 2*xcd+1},
//    time-sliced (all level-2x blocks enqueued before level-2x+1 blocks for that
//    XCD), so the XCD's L2 holds a single level's table at a time -> gathers
//    become L2 hits (34.5 TB/s) instead of L2-fill misses (3.7 TB/s observed).
//  - 4 points/thread -> 16 independent gathers in flight (4x MLP of R0 kernel).
//  - x loads and out stores are NON-TEMPORAL so the streaming traffic doesn't
//    evict the table from L2. Out stores are scattered (stride 128 B, 8 B each);
//    accepted cost, watch WRITE_SIZE.
__global__ __launch_bounds__(THREADS) void hashgrid2d_lvlpart(
    const float* __restrict__ x,
    const float* __restrict__ tables,
    float* __restrict__ out,
    int B, int chunksPerLevel)
{
    int bid  = blockIdx.x;
    int xcd  = bid & 7;                    // round-robin XCD assignment heuristic
    int seq  = bid >> 3;                   // position in this XCD's queue
    int half = (seq >= chunksPerLevel) ? 1 : 0;
    int level = 2 * xcd + half;
    int chunk = seq - half * chunksPerLevel;

    const vf2* __restrict__ tbl =
        reinterpret_cast<const vf2*>(tables) + ((size_t)level << LOG2T);
    const vf2* __restrict__ x2  = reinterpret_cast<const vf2*>(x);
    vf2* __restrict__ out2      = reinterpret_cast<vf2*>(out);

    float res = (float)(256 << level);     // exact power of two per level

    int base = chunk * PTS_PER_BLOCK + (int)threadIdx.x;

    // ---- issue phase: load x, compute indices, issue all gathers ----
    vf2 e00[PTS_PER_THREAD], e01[PTS_PER_THREAD], e10[PTS_PER_THREAD], e11[PTS_PER_THREAD];
    float w0[PTS_PER_THREAD], w1[PTS_PER_THREAD];
    int   bidx[PTS_PER_THREAD];

    #pragma unroll
    for (int k = 0; k < PTS_PER_THREAD; ++k) {
        int b = base + k * THREADS;
        bidx[k] = b;
        if (b >= B) { b = B - 1; }                 // clamp; result discarded
        vf2 xy = __builtin_nontemporal_load(&x2[b]);

        float xs0 = xy.x * res;                    // exact: pow2 scale
        float xs1 = xy.y * res;
        float v0 = floorf(xs0), v1 = floorf(xs1);
        w0[k] = xs0 - v0;
        w1[k] = xs1 - v1;

        unsigned i0 = (unsigned)(int)v0;
        unsigned i1 = (unsigned)(int)v1;
        unsigned hy0 = i1 * PRIME1;
        unsigned hy1 = hy0 + PRIME1;               // (i1+1)*PRIME1

        unsigned idx00 = ( i0       ^ hy0) & TMASK;
        unsigned idx01 = ( i0       ^ hy1) & TMASK;
        unsigned idx10 = ((i0 + 1u) ^ hy0) & TMASK;
        unsigned idx11 = ((i0 + 1u) ^ hy1) & TMASK;

        e00[k] = tbl[idx00];
        e01[k] = tbl[idx01];
        e10[k] = tbl[idx10];
        e11[k] = tbl[idx11];
    }

    // ---- consume phase: bilinear lerp + scattered nt store ----
    #pragma unroll
    for (int k = 0; k < PTS_PER_THREAD; ++k) {
        int b = bidx[k];
        if (b >= B) continue;
        float omw0 = 1.0f - w0[k], omw1 = 1.0f - w1[k];
        float c0x = e00[k].x * omw0 + e10[k].x * w0[k];
        float c0y = e00[k].y * omw0 + e10[k].y * w0[k];
        float c1x = e01[k].x * omw0 + e11[k].x * w0[k];
        float c1y = e01[k].y * omw0 + e11[k].y * w0[k];
        vf2 o;
        o.x = c0x * omw1 + c1x * w1[k];
        o.y = c0y * omw1 + c1y * w1[k];
        __builtin_nontemporal_store(o, &out2[(size_t)b * NLEVELS + level]);
    }
}

extern "C" void kernel_launch(void* const* d_in, const int* in_sizes, int n_in,
                              void* d_out, int out_size, void* d_ws, size_t ws_size,
                              hipStream_t stream) {
    const float* x      = (const float*)d_in[0];
    const float* tables = (const float*)d_in[1];
    float* out          = (float*)d_out;
    int B = in_sizes[0] / 2;                         // x is (B, 2)

    int chunksPerLevel = (B + PTS_PER_BLOCK - 1) / PTS_PER_BLOCK;
    int grid = NLEVELS * chunksPerLevel;             // = 8 XCDs * 2 levels * chunks
    hashgrid2d_lvlpart<<<grid, THREADS, 0, stream>>>(x, tables, out, B, chunksPerLevel);
}